// Round 7
// baseline (348.568 us; speedup 1.0000x reference)
//
#include <hip/hip_runtime.h>
#include <hip/hip_bf16.h>

// DecoderRNN: B=64, S=32, T=31 decode steps, E=D=512, V=10000
// Pipeline: k_prep(+wlstm) -> k_xproj -> k_mega (rec waves + flag-gated
// classifier waves fused in one dispatch)

typedef __attribute__((ext_vector_type(4))) float f32x4;
typedef __attribute__((ext_vector_type(8))) short short8;

#define BB 64
#define SS 32
#define TT 31
#define EE 512
#define VV 10000
#define NTILE 157                       // ceil(10000/64)

__device__ __forceinline__ float sigf(float x){ return 1.0f/(1.0f + __expf(-x)); }
__device__ __forceinline__ float tanh_(float x){
  x = fminf(15.f, fmaxf(-15.f, x));
  float e = __expf(2.f*x);
  return (e-1.f)/(e+1.f);
}
__device__ __forceinline__ unsigned short f2bf(float x){
  __hip_bfloat16 h = __float2bfloat16(x);
  return __builtin_bit_cast(unsigned short, h);
}
// Coherent (MALL-visible) memops — proven R4 helpers.
__device__ __forceinline__ short8 ld16_coh(const void* p){
  short8 r;
  asm volatile("global_load_dwordx4 %0, %1, off sc0 sc1" : "=v"(r) : "v"(p) : "memory");
  return r;
}
__device__ __forceinline__ void st8_coh(void* p, unsigned long long v){
  asm volatile("global_store_dwordx2 %0, %1, off sc0 sc1" :: "v"(p), "v"(v) : "memory");
}

// ---------------------------------------------------------------------------
// Kernel 1: bf16 conversions (dec_wih, dec_whh) + gathered Xa + h0 into hbuf,
// plus (blocks >= NPREP) the hidden-size-1 "w" LSTM + dl + flag init.
// ---------------------------------------------------------------------------
#define NPREP 2048
__global__ __launch_bounds__(256) void k_prep(
    const float* __restrict__ dwih, const float* __restrict__ dwhh,
    const float* __restrict__ emb, const int* __restrict__ cap,
    const float* __restrict__ enc,
    __hip_bfloat16* __restrict__ wihbf, __hip_bfloat16* __restrict__ whhbf,
    __hip_bfloat16* __restrict__ xa, __hip_bfloat16* __restrict__ h0,
    const int* __restrict__ caplen,
    const float* __restrict__ wwih, const float* __restrict__ wwhh,
    const float* __restrict__ wbih, const float* __restrict__ wbhh,
    const float* __restrict__ ihw, const float* __restrict__ ihb,
    const float* __restrict__ icw, const float* __restrict__ icb,
    float* __restrict__ wgt, unsigned* __restrict__ flags,
    float* __restrict__ dl_out)
{
  if (blockIdx.x >= NPREP){
    // ---- w-LSTM block for batch row b ----
    int b = blockIdx.x - NPREP;
    int w = threadIdx.x >> 6, lane = threadIdx.x & 63;
    __shared__ float sv[6];   // ew[0..3], wh0, wc0

    float p = 0.f;
    for (int k = lane; k < EE; k += 64) p += enc[b*EE + k] * wwih[w*EE + k];
    #pragma unroll
    for (int off = 32; off; off >>= 1) p += __shfl_down(p, off, 64);
    if (lane == 0) sv[w] = p;

    if (w < 2){
      const float* iw = (w == 0) ? ihw : icw;
      float q = 0.f;
      for (int k = lane; k < EE; k += 64) q += enc[b*EE + k] * iw[k];
      #pragma unroll
      for (int off = 32; off; off >>= 1) q += __shfl_down(q, off, 64);
      if (lane == 0) sv[4 + w] = q + ((w == 0) ? ihb[0] : icb[0]);
    }
    __syncthreads();

    if (threadIdx.x == 0){
      float wh = sv[4], wc = sv[5];
      int dl = caplen[b] - 1;
      for (int t = 0; t < TT; t++){
        float gi = sv[0] + wh*wwhh[0] + wbih[0] + wbhh[0];
        float gf = sv[1] + wh*wwhh[1] + wbih[1] + wbhh[1];
        float gg = sv[2] + wh*wwhh[2] + wbih[2] + wbhh[2];
        float go = sv[3] + wh*wwhh[3] + wbih[3] + wbhh[3];
        float wc2 = sigf(gf)*wc + sigf(gi)*tanh_(gg);
        float wh2 = sigf(go)*tanh_(wc2);
        float m = (dl > t) ? 1.f : 0.f;
        wgt[b*TT + t] = sigf(wh2) * m;
        if (dl > t){ wh = wh2; wc = wc2; }
      }
      dl_out[b] = (float)dl;
    }
    if (b == 0) for (int i = threadIdx.x; i < 4096; i += 256) flags[i] = 0;
    return;
  }

  // ---- conversion blocks ----
  const int c1 = 2097152;              // dec_wih [2048][1024]
  const int c2 = c1 + 1048576;         // dec_whh [2048][512]
  const int c3 = c2 + 2031616;         // Xa      [1984][1024] (row r = t*64+b)
  const int c4 = c3 + 32768;           // h0      [64][512] (buffer 0 of hbuf)
  for (int i = blockIdx.x*blockDim.x + threadIdx.x; i < c4; i += NPREP*256){
    float v; __hip_bfloat16* dst;
    if (i < c1){ v = dwih[i]; dst = wihbf + i; }
    else if (i < c2){ int j = i - c1; v = dwhh[j]; dst = whhbf + j; }
    else if (i < c3){
      int j = i - c2; int r = j >> 10, k = j & 1023, t = r >> 6, b = r & 63;
      v = (k < 512) ? emb[(size_t)cap[b*SS + t]*EE + k] : enc[b*EE + (k - 512)];
      dst = xa + j;
    } else { int j = i - c3; v = enc[j]; dst = h0 + j; }
    *dst = __float2bfloat16(v);
  }
}

// ---------------------------------------------------------------------------
// Kernel 2: x-projection GEMM: Xp[r][n] = Xa[r] . wih[n] + bih[n] + bhh[n]
// ---------------------------------------------------------------------------
__global__ __launch_bounds__(256) void k_xproj(
    const __hip_bfloat16* __restrict__ xa, const __hip_bfloat16* __restrict__ wihbf,
    const float* __restrict__ bih, const float* __restrict__ bhh,
    float* __restrict__ xp)
{
  int bm = blockIdx.y;                 // 0..30
  int bn = blockIdx.x;                 // 0..7
  int w = threadIdx.x >> 6, lane = threadIdx.x & 63;
  int col = lane & 15, kg = lane >> 4;
  int m0 = bm*64;
  int n0 = bn*256 + w*64;

  f32x4 acc[4][4] = {};
  for (int kk = 0; kk < 32; kk++){
    short8 a[4], bfr[4];
    #pragma unroll
    for (int i = 0; i < 4; i++){
      a[i]   = *(const short8*)(xa    + (size_t)(m0 + i*16 + col)*1024 + kk*32 + kg*8);
      bfr[i] = *(const short8*)(wihbf + (size_t)(n0 + i*16 + col)*1024 + kk*32 + kg*8);
    }
    #pragma unroll
    for (int mt = 0; mt < 4; mt++)
      #pragma unroll
      for (int nt = 0; nt < 4; nt++)
        acc[mt][nt] = __builtin_amdgcn_mfma_f32_16x16x32_bf16(a[mt], bfr[nt], acc[mt][nt], 0, 0, 0);
  }
  float badd[4]; int ncol[4];
  #pragma unroll
  for (int nt = 0; nt < 4; nt++){ int n = n0 + nt*16 + col; ncol[nt] = n; badd[nt] = bih[n] + bhh[n]; }
  #pragma unroll
  for (int mt = 0; mt < 4; mt++)
    #pragma unroll
    for (int rg = 0; rg < 4; rg++){
      int r = m0 + mt*16 + 4*kg + rg;
      #pragma unroll
      for (int nt = 0; nt < 4; nt++)
        xp[(size_t)r*2048 + ncol[nt]] = acc[mt][nt][rg] + badd[nt];
    }
}

// ---------------------------------------------------------------------------
// Kernel 3 (mega): blocks 0..127 = R4-proven persistent recurrence;
// blocks 128..511 = classifier waves, gated per t-block on the step flags.
// hout is t-major ([t*64+b][512]) and written sc0/sc1 + drained before the
// flag, so cls waves' first-touch normal loads are guaranteed fresh.
// ---------------------------------------------------------------------------
__global__ __launch_bounds__(64, 1) void k_mega(
    const __hip_bfloat16* __restrict__ whhbf,   // [2048][512]
    const float* __restrict__ xp,               // [T*64][2048]
    const float* __restrict__ enc,              // [64][512]
    const int* __restrict__ caplen,
    char* __restrict__ hbuf,                    // [2][64][512] bf16 ping-pong
    __hip_bfloat16* __restrict__ hout,          // [T*64][512] t-major
    unsigned* __restrict__ flags,               // 128 lines x 32 u32
    const float* __restrict__ clsw,             // [10000][512] f32
    const float* __restrict__ clsb,
    const float* __restrict__ wgt,              // [1984] b-major (b*31+t)
    float* __restrict__ preds, float* __restrict__ wout)
{
  const int bid = blockIdx.x;
  const int lane = threadIdx.x;
  const int col = lane & 15, kg = lane >> 4;

  if (bid >= 128){
    // ================= classifier waves =================
    const int cw = bid - 128;            // 0..383
    for (int tau = cw; tau < TT*NTILE; tau += 384){
      int mt = tau / NTILE, nt = tau - mt*NTILE;

      // gate: all 128 rec waves finished step mt (flag value mt+1)
      {
        const unsigned tgt = (unsigned)(mt + 1);
        while (1){
          unsigned v0 = __hip_atomic_load(flags + (size_t)lane*32,
                                          __ATOMIC_RELAXED, __HIP_MEMORY_SCOPE_AGENT);
          unsigned v1 = __hip_atomic_load(flags + (size_t)(lane + 64)*32,
                                          __ATOMIC_RELAXED, __HIP_MEMORY_SCOPE_AGENT);
          unsigned v = min(v0, v1);
          v = min(v, (unsigned)__shfl_xor((int)v, 1, 64));
          v = min(v, (unsigned)__shfl_xor((int)v, 2, 64));
          v = min(v, (unsigned)__shfl_xor((int)v, 4, 64));
          v = min(v, (unsigned)__shfl_xor((int)v, 8, 64));
          v = min(v, (unsigned)__shfl_xor((int)v, 16, 64));
          v = min(v, (unsigned)__shfl_xor((int)v, 32, 64));
          if (v >= tgt) break;
          __builtin_amdgcn_s_sleep(2);
        }
        asm volatile("" ::: "memory");   // no hout loads hoisted above gate
      }

      int brow[4]; int vcol[4]; bool vok[4]; float cb[4];
      #pragma unroll
      for (int i = 0; i < 4; i++) brow[i] = min(nt*64 + i*16 + col, VV - 1);
      #pragma unroll
      for (int ni = 0; ni < 4; ni++){
        int v = nt*64 + ni*16 + col; vcol[ni] = v; vok[ni] = (v < VV);
        cb[ni] = vok[ni] ? clsb[v] : 0.f;
      }

      const __hip_bfloat16* hbase = hout + (size_t)(mt*64)*512;
      f32x4 acc[4][4] = {};
      for (int kk = 0; kk < 16; kk++){
        short8 a[4], bfr[4];
        #pragma unroll
        for (int i = 0; i < 4; i++)
          a[i] = *(const short8*)(hbase + (size_t)(i*16 + col)*512 + kk*32 + kg*8);
        #pragma unroll
        for (int i = 0; i < 4; i++){
          const float* wr = clsw + (size_t)brow[i]*512 + kk*32 + kg*8;
          f32x4 w0 = *(const f32x4*)wr;
          f32x4 w1 = *(const f32x4*)(wr + 4);
          short8 t8;
          t8[0] = (short)f2bf(w0.x); t8[1] = (short)f2bf(w0.y);
          t8[2] = (short)f2bf(w0.z); t8[3] = (short)f2bf(w0.w);
          t8[4] = (short)f2bf(w1.x); t8[5] = (short)f2bf(w1.y);
          t8[6] = (short)f2bf(w1.z); t8[7] = (short)f2bf(w1.w);
          bfr[i] = t8;
        }
        #pragma unroll
        for (int mi = 0; mi < 4; mi++)
          #pragma unroll
          for (int ni = 0; ni < 4; ni++)
            acc[mi][ni] = __builtin_amdgcn_mfma_f32_16x16x32_bf16(a[mi], bfr[ni], acc[mi][ni], 0, 0, 0);
      }

      #pragma unroll
      for (int mi = 0; mi < 4; mi++)
        #pragma unroll
        for (int rg = 0; rg < 4; rg++){
          int bidx = mi*16 + 4*kg + rg;      // batch row b (tile row)
          int r_out = bidx*TT + mt;          // output row b*31 + t
          float wv = wgt[r_out];
          float mf = (wv > 0.f) ? 1.f : 0.f;
          size_t obase = (size_t)r_out*VV;
          #pragma unroll
          for (int ni = 0; ni < 4; ni++){
            if (!vok[ni]) continue;
            preds[obase + vcol[ni]] = (acc[mi][ni][rg] + cb[ni]) * mf;
            wout [obase + vcol[ni]] = wv;
          }
        }
    }
    return;
  }

  // ================= recurrence waves (R4-proven body) =================
  const int g = bid >> 5, s = bid & 31;
  const int d0 = s*16;
  const int b  = g*16 + col;           // this lane's batch row
  const int dbase = d0 + 4*kg;         // 4 consecutive d owned by this lane
  const int pme = (dbase >> 2);        // u64 index within a 512-bf16 row

  // Persistent A fragments: Whh rows {q*512 + d0 + col}, K=512 (256 regs)
  short8 Aq[4][16];
  #pragma unroll
  for (int q = 0; q < 4; q++){
    const __hip_bfloat16* wrow = whhbf + (size_t)(q*512 + d0 + col)*512;
    #pragma unroll
    for (int kk = 0; kk < 16; kk++)
      Aq[q][kk] = *(const short8*)(wrow + kk*32 + kg*8);
  }
  #pragma unroll
  for (int q = 0; q < 4; q++)
    #pragma unroll
    for (int kk = 0; kk < 16; kk++)
      asm volatile("" : "+v"(Aq[q][kk]));   // pin in registers

  float hst[4], cst[4];
  #pragma unroll
  for (int j = 0; j < 4; j++){
    float e0 = enc[(size_t)b*EE + dbase + j];
    hst[j] = e0; cst[j] = e0;
  }
  const int dl = caplen[b] - 1;
  unsigned* myflag = flags + (size_t)(g*32 + s)*32;
  const unsigned* pollflag = flags + (size_t)(g*32 + (lane & 31))*32;

  f32x4 xg[4];
  #pragma unroll
  for (int q = 0; q < 4; q++)
    xg[q] = *(const f32x4*)(xp + (size_t)b*2048 + q*512 + dbase);

  for (int t = 0; t < TT; t++){
    if (t > 0){
      const unsigned tgt = (unsigned)t;
      while (1){
        unsigned v = __hip_atomic_load(pollflag, __ATOMIC_RELAXED, __HIP_MEMORY_SCOPE_AGENT);
        v = min(v, (unsigned)__shfl_xor((int)v, 1, 64));
        v = min(v, (unsigned)__shfl_xor((int)v, 2, 64));
        v = min(v, (unsigned)__shfl_xor((int)v, 4, 64));
        v = min(v, (unsigned)__shfl_xor((int)v, 8, 64));
        v = min(v, (unsigned)__shfl_xor((int)v, 16, 64));
        if (v >= tgt) break;
        __builtin_amdgcn_s_sleep(1);
      }
    }

    // Issue B-fragment loads (coherent, pipelined)
    const char* hc = hbuf + (size_t)(t & 1)*65536 + (size_t)b*1024 + kg*16;
    short8 Bf[16];
    #pragma unroll
    for (int kk = 0; kk < 16; kk++)
      Bf[kk] = ld16_coh(hc + kk*64);

    // prefetch next step's gate projections (overlaps load latency)
    f32x4 xgn[4];
    if (t + 1 < TT){
      #pragma unroll
      for (int q = 0; q < 4; q++)
        xgn[q] = *(const f32x4*)(xp + (size_t)((t+1)*BB + b)*2048 + q*512 + dbase);
    }

    asm volatile("s_waitcnt vmcnt(0)" ::: "memory");
    __builtin_amdgcn_sched_barrier(0);

    f32x4 acc[4] = {};
    #pragma unroll
    for (int kk = 0; kk < 16; kk++)
      #pragma unroll
      for (int q = 0; q < 4; q++)
        acc[q] = __builtin_amdgcn_mfma_f32_16x16x32_bf16(Aq[q][kk], Bf[kk], acc[q], 0, 0, 0);

    const bool act = dl > t;
    unsigned long long hpack = 0, spack = 0;
    #pragma unroll
    for (int j = 0; j < 4; j++){
      float gi = acc[0][j] + xg[0][j];
      float gf = acc[1][j] + xg[1][j];
      float gg = acc[2][j] + xg[2][j];
      float go = acc[3][j] + xg[3][j];
      float c2 = sigf(gf)*cst[j] + sigf(gi)*tanh_(gg);
      float h2 = sigf(go)*tanh_(c2);
      if (act){ cst[j] = c2; hst[j] = h2; }
      hpack |= (unsigned long long)f2bf(h2)     << (16*j);
      spack |= (unsigned long long)f2bf(hst[j]) << (16*j);
    }

    // masked state -> ping-pong exchange (coherent)
    if (t < TT - 1)
      st8_coh(hbuf + (size_t)((t + 1) & 1)*65536 + (size_t)b*1024 + (size_t)dbase*2, spack);
    // fresh h2 -> hout (t-major, write-through so cls waves see it via MALL)
    st8_coh((unsigned long long*)hout + ((size_t)t*BB + b)*128 + pme, hpack);

    asm volatile("s_waitcnt vmcnt(0)" ::: "memory");
    if (lane == 0)
      __hip_atomic_store(myflag, (unsigned)(t + 1),
                         __ATOMIC_RELAXED, __HIP_MEMORY_SCOPE_AGENT);

    if (t + 1 < TT){
      #pragma unroll
      for (int q = 0; q < 4; q++) xg[q] = xgn[q];
    }
  }
}

// ---------------------------------------------------------------------------
extern "C" void kernel_launch(void* const* d_in, const int* in_sizes, int n_in,
                              void* d_out, int out_size, void* d_ws, size_t ws_size,
                              hipStream_t stream) {
  const float* enc    = (const float*)d_in[0];
  const int*   cap    = (const int*)  d_in[1];
  const int*   caplen = (const int*)  d_in[2];
  const float* emb    = (const float*)d_in[3];
  const float* dwih   = (const float*)d_in[4];
  const float* dwhh   = (const float*)d_in[5];
  const float* dbih   = (const float*)d_in[6];
  const float* dbhh   = (const float*)d_in[7];
  const float* wwih   = (const float*)d_in[8];
  const float* wwhh   = (const float*)d_in[9];
  const float* wbih   = (const float*)d_in[10];
  const float* wbhh   = (const float*)d_in[11];
  const float* ihw    = (const float*)d_in[12];
  const float* ihb    = (const float*)d_in[13];
  const float* icw    = (const float*)d_in[14];
  const float* icb    = (const float*)d_in[15];
  const float* clsw   = (const float*)d_in[16];
  const float* clsb   = (const float*)d_in[17];

  float* preds  = (float*)d_out;                       // [64][31][10000]
  float* dl_out = preds + (size_t)BB*TT*VV;            // [64]
  float* wout   = dl_out + BB;                         // [64][31][10000]

  char* ws = (char*)d_ws;
  float*          wgt   = (float*)         (ws + 0);          // 1984 f32 (pad 8192)
  unsigned*       flags = (unsigned*)      (ws + 8192);       // 4096 u32 (16 KB)
  __hip_bfloat16* wihbf = (__hip_bfloat16*)(ws + 24576);      //  4,194,304 B
  __hip_bfloat16* whhbf = (__hip_bfloat16*)(ws + 4218880);    //  2,097,152 B
  __hip_bfloat16* xa    = (__hip_bfloat16*)(ws + 6316032);    //  4,063,232 B
  float*          xp    = (float*)         (ws + 10379264);   // 16,252,928 B
  char*           hbuf  = (char*)          (ws + 26632192);   //    131,072 B
  __hip_bfloat16* hout  = (__hip_bfloat16*)(ws + 26763264);   //  2,031,616 B
  // total ~28.8 MB of d_ws

  k_prep <<<NPREP + BB, 256, 0, stream>>>(dwih, dwhh, emb, cap, enc,
                                          wihbf, whhbf, xa,
                                          (__hip_bfloat16*)hbuf,
                                          caplen, wwih, wwhh, wbih, wbhh,
                                          ihw, ihb, icw, icb, wgt, flags, dl_out);
  k_xproj<<<dim3(8, 31), 256, 0, stream>>>(xa, wihbf, dbih, dbhh, xp);
  k_mega <<<512, 64, 0, stream>>>(whhbf, xp, enc, caplen, hbuf, hout, flags,
                                  clsw, clsb, wgt, preds, wout);
}

// Round 8
// 287.919 us; speedup vs baseline: 1.2106x; 1.2106x over previous
//
#include <hip/hip_runtime.h>
#include <hip/hip_bf16.h>

// DecoderRNN: B=64, S=32, T=31 decode steps, E=D=512, V=10000
// Pipeline: k_prep(+wlstm) -> k_xproj -> k_rec (persistent, short-chain sync)
//           -> k_cls.  (R4 structure; R7 mega-fusion regressed: BW contention.)

typedef __attribute__((ext_vector_type(4))) float f32x4;
typedef __attribute__((ext_vector_type(8))) short short8;
typedef __attribute__((ext_vector_type(4))) unsigned short u16x4;

#define BB 64
#define SS 32
#define TT 31
#define EE 512
#define VV 10000

__device__ __forceinline__ float sigf(float x){ return 1.0f/(1.0f + __expf(-x)); }
__device__ __forceinline__ float tanh_(float x){
  x = fminf(15.f, fmaxf(-15.f, x));
  float e = __expf(2.f*x);
  return (e-1.f)/(e+1.f);
}
__device__ __forceinline__ unsigned short f2bf(float x){
  __hip_bfloat16 h = __float2bfloat16(x);
  return __builtin_bit_cast(unsigned short, h);
}
// Coherent (MALL-visible) memops — proven R4 helpers.
__device__ __forceinline__ short8 ld16_coh(const void* p){
  short8 r;
  asm volatile("global_load_dwordx4 %0, %1, off sc0 sc1" : "=v"(r) : "v"(p) : "memory");
  return r;
}
__device__ __forceinline__ void st8_coh(void* p, unsigned long long v){
  asm volatile("global_store_dwordx2 %0, %1, off sc0 sc1" :: "v"(p), "v"(v) : "memory");
}

// ---------------------------------------------------------------------------
// Kernel 1: bf16 conversions (dec_wih, dec_whh) + gathered Xa + h0 into hbuf,
// plus (blocks >= NPREP) the hidden-size-1 "w" LSTM + dl + flag init.
// ---------------------------------------------------------------------------
#define NPREP 2048
__global__ __launch_bounds__(256) void k_prep(
    const float* __restrict__ dwih, const float* __restrict__ dwhh,
    const float* __restrict__ emb, const int* __restrict__ cap,
    const float* __restrict__ enc,
    __hip_bfloat16* __restrict__ wihbf, __hip_bfloat16* __restrict__ whhbf,
    __hip_bfloat16* __restrict__ xa, __hip_bfloat16* __restrict__ h0,
    const int* __restrict__ caplen,
    const float* __restrict__ wwih, const float* __restrict__ wwhh,
    const float* __restrict__ wbih, const float* __restrict__ wbhh,
    const float* __restrict__ ihw, const float* __restrict__ ihb,
    const float* __restrict__ icw, const float* __restrict__ icb,
    float* __restrict__ wgt, unsigned* __restrict__ flags,
    float* __restrict__ dl_out)
{
  if (blockIdx.x >= NPREP){
    // ---- w-LSTM block for batch row b ----
    int b = blockIdx.x - NPREP;
    int w = threadIdx.x >> 6, lane = threadIdx.x & 63;
    __shared__ float sv[6];   // ew[0..3], wh0, wc0

    float p = 0.f;
    for (int k = lane; k < EE; k += 64) p += enc[b*EE + k] * wwih[w*EE + k];
    #pragma unroll
    for (int off = 32; off; off >>= 1) p += __shfl_down(p, off, 64);
    if (lane == 0) sv[w] = p;

    if (w < 2){
      const float* iw = (w == 0) ? ihw : icw;
      float q = 0.f;
      for (int k = lane; k < EE; k += 64) q += enc[b*EE + k] * iw[k];
      #pragma unroll
      for (int off = 32; off; off >>= 1) q += __shfl_down(q, off, 64);
      if (lane == 0) sv[4 + w] = q + ((w == 0) ? ihb[0] : icb[0]);
    }
    __syncthreads();

    if (threadIdx.x == 0){
      float wh = sv[4], wc = sv[5];
      int dl = caplen[b] - 1;
      for (int t = 0; t < TT; t++){
        float gi = sv[0] + wh*wwhh[0] + wbih[0] + wbhh[0];
        float gf = sv[1] + wh*wwhh[1] + wbih[1] + wbhh[1];
        float gg = sv[2] + wh*wwhh[2] + wbih[2] + wbhh[2];
        float go = sv[3] + wh*wwhh[3] + wbih[3] + wbhh[3];
        float wc2 = sigf(gf)*wc + sigf(gi)*tanh_(gg);
        float wh2 = sigf(go)*tanh_(wc2);
        float m = (dl > t) ? 1.f : 0.f;
        wgt[b*TT + t] = sigf(wh2) * m;
        if (dl > t){ wh = wh2; wc = wc2; }
      }
      dl_out[b] = (float)dl;
    }
    if (b == 0) for (int i = threadIdx.x; i < 4096; i += 256) flags[i] = 0;
    return;
  }

  // ---- conversion blocks ----
  const int c1 = 2097152;              // dec_wih [2048][1024]
  const int c2 = c1 + 1048576;         // dec_whh [2048][512]
  const int c3 = c2 + 2031616;         // Xa      [1984][1024] (row r = t*64+b)
  const int c4 = c3 + 32768;           // h0      [64][512] (buffer 0 of hbuf)
  for (int i = blockIdx.x*blockDim.x + threadIdx.x; i < c4; i += NPREP*256){
    float v; __hip_bfloat16* dst;
    if (i < c1){ v = dwih[i]; dst = wihbf + i; }
    else if (i < c2){ int j = i - c1; v = dwhh[j]; dst = whhbf + j; }
    else if (i < c3){
      int j = i - c2; int r = j >> 10, k = j & 1023, t = r >> 6, b = r & 63;
      v = (k < 512) ? emb[(size_t)cap[b*SS + t]*EE + k] : enc[b*EE + (k - 512)];
      dst = xa + j;
    } else { int j = i - c3; v = enc[j]; dst = h0 + j; }
    *dst = __float2bfloat16(v);
  }
}

// ---------------------------------------------------------------------------
// Kernel 2: x-projection GEMM: Xp[r][n] = Xa[r] . wih[n] + bih[n] + bhh[n]
// ---------------------------------------------------------------------------
__global__ __launch_bounds__(256) void k_xproj(
    const __hip_bfloat16* __restrict__ xa, const __hip_bfloat16* __restrict__ wihbf,
    const float* __restrict__ bih, const float* __restrict__ bhh,
    float* __restrict__ xp)
{
  int bm = blockIdx.y;                 // 0..30
  int bn = blockIdx.x;                 // 0..7
  int w = threadIdx.x >> 6, lane = threadIdx.x & 63;
  int col = lane & 15, kg = lane >> 4;
  int m0 = bm*64;
  int n0 = bn*256 + w*64;

  f32x4 acc[4][4] = {};
  for (int kk = 0; kk < 32; kk++){
    short8 a[4], bfr[4];
    #pragma unroll
    for (int i = 0; i < 4; i++){
      a[i]   = *(const short8*)(xa    + (size_t)(m0 + i*16 + col)*1024 + kk*32 + kg*8);
      bfr[i] = *(const short8*)(wihbf + (size_t)(n0 + i*16 + col)*1024 + kk*32 + kg*8);
    }
    #pragma unroll
    for (int mt = 0; mt < 4; mt++)
      #pragma unroll
      for (int nt = 0; nt < 4; nt++)
        acc[mt][nt] = __builtin_amdgcn_mfma_f32_16x16x32_bf16(a[mt], bfr[nt], acc[mt][nt], 0, 0, 0);
  }
  float badd[4]; int ncol[4];
  #pragma unroll
  for (int nt = 0; nt < 4; nt++){ int n = n0 + nt*16 + col; ncol[nt] = n; badd[nt] = bih[n] + bhh[n]; }
  #pragma unroll
  for (int mt = 0; mt < 4; mt++)
    #pragma unroll
    for (int rg = 0; rg < 4; rg++){
      int r = m0 + mt*16 + 4*kg + rg;
      #pragma unroll
      for (int nt = 0; nt < 4; nt++)
        xp[(size_t)r*2048 + ncol[nt]] = acc[mt][nt][rg] + badd[nt];
    }
}

// ---------------------------------------------------------------------------
// Kernel 3: persistent recurrence (blocks 0..127, 1 wave each) + fused
// cls_w->bf16 conversion (blocks 128..511).
// Critical chain per step: poll -> Bf loads -> vmcnt(0) -> MFMA -> pointwise
// -> exchange store -> vmcnt(4) [waits ONLY the store; xgn prefetch issued
// after it stays in flight] -> flag.  hout store is off-chain (after flag).
// xg double-buffered (xgA/xgB) with 2-step unroll: no end-of-step wait.
// ---------------------------------------------------------------------------
__global__ __launch_bounds__(64, 1) void k_rec(
    const __hip_bfloat16* __restrict__ whhbf,   // [2048][512]
    const float* __restrict__ xp,               // [T*64][2048]
    const float* __restrict__ enc,              // [64][512]
    const int* __restrict__ caplen,
    char* __restrict__ hbuf,                    // [2][64][512] bf16 ping-pong
    __hip_bfloat16* __restrict__ hout,          // [64][T][512] b-major
    unsigned* __restrict__ flags,               // 128 lines x 32 u32
    const float* __restrict__ clsw,
    __hip_bfloat16* __restrict__ clsbf)
{
  const int bid = blockIdx.x;
  const int lane = threadIdx.x;

  if (bid >= 128){                     // ---- converter blocks ----
    const int n4 = 1280000;            // 5,120,000 / 4
    for (int i = (bid - 128)*64 + lane; i < n4; i += 384*64){
      f32x4 v = ((const f32x4*)clsw)[i];
      u16x4 o;
      o.x = f2bf(v.x); o.y = f2bf(v.y); o.z = f2bf(v.z); o.w = f2bf(v.w);
      ((u16x4*)clsbf)[i] = o;
    }
    return;
  }

  // ---- recurrence ----
  const int g = bid >> 5, s = bid & 31;
  const int col = lane & 15, kg = lane >> 4;
  const int d0 = s*16;
  const int b  = g*16 + col;           // this lane's batch row
  const int dbase = d0 + 4*kg;         // 4 consecutive d owned by this lane
  const int pme = (dbase >> 2);        // u64 index within a 512-bf16 row

  // Persistent A fragments: Whh rows {q*512 + d0 + col}, K=512 (256 regs)
  short8 Aq[4][16];
  #pragma unroll
  for (int q = 0; q < 4; q++){
    const __hip_bfloat16* wrow = whhbf + (size_t)(q*512 + d0 + col)*512;
    #pragma unroll
    for (int kk = 0; kk < 16; kk++)
      Aq[q][kk] = *(const short8*)(wrow + kk*32 + kg*8);
  }
  #pragma unroll
  for (int q = 0; q < 4; q++)
    #pragma unroll
    for (int kk = 0; kk < 16; kk++)
      asm volatile("" : "+v"(Aq[q][kk]));   // pin in registers

  float hst[4], cst[4];
  #pragma unroll
  for (int j = 0; j < 4; j++){
    float e0 = enc[(size_t)b*EE + dbase + j];
    hst[j] = e0; cst[j] = e0;
  }
  const int dl = caplen[b] - 1;
  unsigned* myflag = flags + (size_t)(g*32 + s)*32;
  const unsigned* pollflag = flags + (size_t)(g*32 + (lane & 31))*32;

  f32x4 xgA[4], xgB[4];
  #pragma unroll
  for (int q = 0; q < 4; q++)
    xgA[q] = *(const f32x4*)(xp + (size_t)b*2048 + q*512 + dbase);

#define REC_STEP(T, XGU, XGP)                                                  \
  do {                                                                         \
    const int t_ = (T);                                                        \
    if (t_ > 0){                                                               \
      const unsigned tgt = (unsigned)t_;                                       \
      while (1){                                                               \
        unsigned v = __hip_atomic_load(pollflag, __ATOMIC_RELAXED,             \
                                       __HIP_MEMORY_SCOPE_AGENT);              \
        v = min(v, (unsigned)__shfl_xor((int)v, 1, 64));                       \
        v = min(v, (unsigned)__shfl_xor((int)v, 2, 64));                       \
        v = min(v, (unsigned)__shfl_xor((int)v, 4, 64));                       \
        v = min(v, (unsigned)__shfl_xor((int)v, 8, 64));                       \
        v = min(v, (unsigned)__shfl_xor((int)v, 16, 64));                      \
        if (v >= tgt) break;                                                   \
        __builtin_amdgcn_s_sleep(1);                                           \
      }                                                                        \
    }                                                                          \
    const char* hc = hbuf + (size_t)(t_ & 1)*65536 + (size_t)b*1024 + kg*16;   \
    short8 Bf[16];                                                             \
    _Pragma("unroll")                                                          \
    for (int kk = 0; kk < 16; kk++)                                            \
      Bf[kk] = ld16_coh(hc + kk*64);                                           \
    asm volatile("s_waitcnt vmcnt(0)" ::: "memory");                           \
    __builtin_amdgcn_sched_barrier(0);                                         \
    f32x4 acc[4] = {};                                                         \
    _Pragma("unroll")                                                          \
    for (int kk = 0; kk < 16; kk++)                                            \
      _Pragma("unroll")                                                        \
      for (int q = 0; q < 4; q++)                                              \
        acc[q] = __builtin_amdgcn_mfma_f32_16x16x32_bf16(Aq[q][kk], Bf[kk],    \
                                                         acc[q], 0, 0, 0);     \
    const bool act = dl > t_;                                                  \
    unsigned long long hpack = 0, spack = 0;                                   \
    _Pragma("unroll")                                                          \
    for (int j = 0; j < 4; j++){                                               \
      float gi = acc[0][j] + XGU[0][j];                                        \
      float gf = acc[1][j] + XGU[1][j];                                        \
      float gg = acc[2][j] + XGU[2][j];                                        \
      float go = acc[3][j] + XGU[3][j];                                        \
      float c2 = sigf(gf)*cst[j] + sigf(gi)*tanh_(gg);                         \
      float h2 = sigf(go)*tanh_(c2);                                           \
      if (act){ cst[j] = c2; hst[j] = h2; }                                    \
      hpack |= (unsigned long long)f2bf(h2)     << (16*j);                     \
      spack |= (unsigned long long)f2bf(hst[j]) << (16*j);                     \
    }                                                                          \
    if (t_ < TT - 1)                                                           \
      st8_coh(hbuf + (size_t)((t_ + 1) & 1)*65536 + (size_t)b*1024             \
              + (size_t)dbase*2, spack);                                       \
    if (t_ + 1 < TT){                                                          \
      _Pragma("unroll")                                                        \
      for (int q = 0; q < 4; q++)                                              \
        XGP[q] = *(const f32x4*)(xp + (size_t)((t_+1)*BB + b)*2048             \
                                 + q*512 + dbase);                             \
    }                                                                          \
    asm volatile("s_waitcnt vmcnt(4)" ::: "memory");                           \
    if (t_ < TT - 1 && lane == 0)                                              \
      __hip_atomic_store(myflag, (unsigned)(t_ + 1),                           \
                         __ATOMIC_RELAXED, __HIP_MEMORY_SCOPE_AGENT);          \
    ((unsigned long long*)hout)[((size_t)b*TT + t_)*128 + pme] = hpack;        \
  } while (0)

  for (int t2 = 0; t2 < TT - 1; t2 += 2){
    REC_STEP(t2,     xgA, xgB);
    REC_STEP(t2 + 1, xgB, xgA);
  }
  REC_STEP(TT - 1, xgA, xgB);          // TT=31 odd: tail step uses xgA
#undef REC_STEP
}

// ---------------------------------------------------------------------------
// Kernel 4: classifier GEMM fused with mask + weights broadcast.
// ---------------------------------------------------------------------------
__global__ __launch_bounds__(256) void k_cls(
    const __hip_bfloat16* __restrict__ hbf,   // [1984][512] (row r = b*31+t)
    const __hip_bfloat16* __restrict__ wbf,   // [10000][512]
    const float* __restrict__ clsb,
    const float* __restrict__ wgt,            // [1984], ==0 iff masked
    float* __restrict__ preds, float* __restrict__ wout)
{
  int bid = blockIdx.x;
  int bn = bid % 79, bm = bid / 79;
  int w = threadIdx.x >> 6, lane = threadIdx.x & 63;
  int col = lane & 15, kg = lane >> 4;
  int m0 = bm*128 + (w >> 1)*64;
  int n0 = bn*128 + (w & 1)*64;
  if (m0 >= 1984) return;

  int arow[4], brow[4];
  #pragma unroll
  for (int i = 0; i < 4; i++){
    arow[i] = min(m0 + i*16 + col, 1983);
    brow[i] = min(n0 + i*16 + col, 9999);
  }
  f32x4 acc[4][4] = {};
  for (int kk = 0; kk < 16; kk++){
    short8 a[4], b[4];
    #pragma unroll
    for (int i = 0; i < 4; i++){
      a[i] = *(const short8*)(hbf + (size_t)arow[i]*512 + kk*32 + kg*8);
      b[i] = *(const short8*)(wbf + (size_t)brow[i]*512 + kk*32 + kg*8);
    }
    #pragma unroll
    for (int mt = 0; mt < 4; mt++)
      #pragma unroll
      for (int nt = 0; nt < 4; nt++)
        acc[mt][nt] = __builtin_amdgcn_mfma_f32_16x16x32_bf16(a[mt], b[nt], acc[mt][nt], 0, 0, 0);
  }
  float cb[4]; int vcol[4]; bool vok[4];
  #pragma unroll
  for (int nt = 0; nt < 4; nt++){
    int v = n0 + nt*16 + col; vcol[nt] = v; vok[nt] = (v < VV);
    cb[nt] = vok[nt] ? clsb[v] : 0.f;
  }
  #pragma unroll
  for (int mt = 0; mt < 4; mt++)
    #pragma unroll
    for (int rg = 0; rg < 4; rg++){
      int r = m0 + mt*16 + 4*kg + rg;
      if (r >= 1984) continue;
      float wv = wgt[r];
      float mf = (wv > 0.f) ? 1.f : 0.f;
      size_t base = (size_t)r*VV;
      #pragma unroll
      for (int nt = 0; nt < 4; nt++){
        if (!vok[nt]) continue;
        preds[base + vcol[nt]] = (acc[mt][nt][rg] + cb[nt]) * mf;
        wout [base + vcol[nt]] = wv;
      }
    }
}

// ---------------------------------------------------------------------------
extern "C" void kernel_launch(void* const* d_in, const int* in_sizes, int n_in,
                              void* d_out, int out_size, void* d_ws, size_t ws_size,
                              hipStream_t stream) {
  const float* enc    = (const float*)d_in[0];
  const int*   cap    = (const int*)  d_in[1];
  const int*   caplen = (const int*)  d_in[2];
  const float* emb    = (const float*)d_in[3];
  const float* dwih   = (const float*)d_in[4];
  const float* dwhh   = (const float*)d_in[5];
  const float* dbih   = (const float*)d_in[6];
  const float* dbhh   = (const float*)d_in[7];
  const float* wwih   = (const float*)d_in[8];
  const float* wwhh   = (const float*)d_in[9];
  const float* wbih   = (const float*)d_in[10];
  const float* wbhh   = (const float*)d_in[11];
  const float* ihw    = (const float*)d_in[12];
  const float* ihb    = (const float*)d_in[13];
  const float* icw    = (const float*)d_in[14];
  const float* icb    = (const float*)d_in[15];
  const float* clsw   = (const float*)d_in[16];
  const float* clsb   = (const float*)d_in[17];

  float* preds  = (float*)d_out;                       // [64][31][10000]
  float* dl_out = preds + (size_t)BB*TT*VV;            // [64]
  float* wout   = dl_out + BB;                         // [64][31][10000]

  char* ws = (char*)d_ws;
  float*          wgt   = (float*)         (ws + 0);          // 1984 f32 (pad 8192)
  unsigned*       flags = (unsigned*)      (ws + 8192);       // 4096 u32 (16 KB)
  __hip_bfloat16* clsbf = (__hip_bfloat16*)(ws + 24576);      // 10,240,000 B
  __hip_bfloat16* wihbf = (__hip_bfloat16*)(ws + 10264576);   //  4,194,304 B
  __hip_bfloat16* whhbf = (__hip_bfloat16*)(ws + 14458880);   //  2,097,152 B
  __hip_bfloat16* xa    = (__hip_bfloat16*)(ws + 16556032);   //  4,063,232 B
  float*          xp    = (float*)         (ws + 20619264);   // 16,252,928 B
  char*           hbuf  = (char*)          (ws + 36872192);   //    131,072 B
  __hip_bfloat16* hout  = (__hip_bfloat16*)(ws + 37003264);   //  2,031,616 B
  // total ~39.0 MB of d_ws

  k_prep <<<NPREP + BB, 256, 0, stream>>>(dwih, dwhh, emb, cap, enc,
                                          wihbf, whhbf, xa,
                                          (__hip_bfloat16*)hbuf,
                                          caplen, wwih, wwhh, wbih, wbhh,
                                          ihw, ihb, icw, icb, wgt, flags, dl_out);
  k_xproj<<<dim3(8, 31), 256, 0, stream>>>(xa, wihbf, dbih, dbhh, xp);
  k_rec  <<<512, 64, 0, stream>>>(whhbf, xp, enc, caplen, hbuf, hout, flags,
                                  clsw, clsbf);
  k_cls  <<<16*79, 256, 0, stream>>>(hout, clsbf, clsb, wgt, preds, wout);
}